// Round 3
// baseline (4261.258 us; speedup 1.0000x reference)
//
#include <hip/hip_runtime.h>

// S=1024 seq, B=32 batch, H=512 hid, E=512 emb, A=256 att — ALL f32 per reference
#define Sn 1024
#define Bn 32
#define Hn 512
#define En 512
#define An 256

// ---------------- projection: out[b][s][a] = scale*(X[s*B+b][:] . W[a][:] + bias[a])
// X: [S*B][512] f32, W: [256][512] f32. 16 rows/block, 256 threads (col=a=tid).
__global__ __launch_bounds__(256) void proj_kernel(const float* __restrict__ X,
                                                   const float* __restrict__ W,
                                                   const float* __restrict__ bias,
                                                   float* __restrict__ outp){
  __shared__ float xs[16][512];
  int tid = threadIdx.x;
  long r0 = (long)blockIdx.x * 16;
  const float4* src = (const float4*)(X + r0 * 512);   // 16 rows = 2048 float4
  #pragma unroll
  for (int i = 0; i < 8; i++){
    int idx = i * 256 + tid;
    float4 vv = src[idx];
    int row = idx >> 7, col = (idx & 127) * 4;
    *(float4*)&xs[row][col] = vv;
  }
  __syncthreads();
  float acc[16];
  float bz = bias[tid];
  #pragma unroll
  for (int r = 0; r < 16; r++) acc[r] = bz;
  const float4* wrow = (const float4*)(W + (long)tid * 512);
  for (int c = 0; c < 128; c += 2){
    float4 w0 = wrow[c], w1 = wrow[c + 1];
    int e0 = c * 4;
    #pragma unroll
    for (int r = 0; r < 16; r++){
      float4 x0 = *(const float4*)&xs[r][e0];
      float4 x1 = *(const float4*)&xs[r][e0 + 4];
      acc[r] += w0.x*x0.x + w0.y*x0.y + w0.z*x0.z + w0.w*x0.w
              + w1.x*x1.x + w1.y*x1.y + w1.z*x1.z + w1.w*x1.w;
    }
  }
  const float scale = 2.8853900817779268f;  // 2*log2(e): arg pre-scale for exp2-based tanh
  #pragma unroll
  for (int r = 0; r < 16; r++){
    long rr = r0 + r;
    int s = (int)(rr >> 5), b = (int)(rr & 31);      // row = s*32 + b
    outp[((long)(b * Sn + s)) * An + tid] = acc[r] * scale;
  }
}

// ---------------- scores + softmax -> weights[q][k][b] f32 (straight to d_out) ----------------
// block: (qt descending, b). 8 queries/block, 256 threads; thread owns key k = ki*256+tid.
__global__ __launch_bounds__(256) void score_kernel(const float* __restrict__ eat,
                                                    const float* __restrict__ pat,
                                                    const float* __restrict__ vptr,
                                                    float* __restrict__ wout){
  __shared__ float p[8][256];
  __shared__ float v2[256];
  __shared__ float sc[8][1024];
  int tid = threadIdx.x;
  int qt = gridDim.x - 1 - blockIdx.x;   // big-work tiles first
  int b = blockIdx.y;
  #pragma unroll
  for (int q = 0; q < 8; q++){
    int qg = qt * 8 + q;
    int t = qg > 0 ? qg - 1 : 0;
    p[q][tid] = pat[((long)(b * Sn + t)) * An + tid];
  }
  float vv = vptr[tid];
  v2[tid] = 2.0f * vv;
  sc[0][tid] = vv;          // block-local reduction for C = sum(v)
  __syncthreads();
  for (int off = 128; off; off >>= 1){
    if (tid < off) sc[0][tid] += sc[0][tid + off];
    __syncthreads();
  }
  float C = sc[0][0];
  __syncthreads();          // everyone has C before sc is reused for scores
  int Lmax = qt * 8 + 6; if (Lmax < 1) Lmax = 1;   // L of the last query in tile
  for (int ki = 0; ki * 256 < Lmax; ki++){
    int k = ki * 256 + tid;
    if (k < Lmax){
      const float4* ep = (const float4*)(eat + ((long)(b * Sn + k)) * An);
      float acc[8] = {0,0,0,0,0,0,0,0};
      for (int c = 0; c < 32; c++){
        float4 ea = ep[2*c], eb = ep[2*c + 1];
        float e[8] = {ea.x,ea.y,ea.z,ea.w,eb.x,eb.y,eb.z,eb.w};
        const float4* vp = (const float4*)&v2[c * 8];
        float4 va = vp[0], vb = vp[1];
        float vvv[8] = {va.x,va.y,va.z,va.w,vb.x,vb.y,vb.z,vb.w};
        #pragma unroll
        for (int q = 0; q < 8; q++){
          const float4* pp = (const float4*)&p[q][c * 8];
          float4 p0 = pp[0], p1 = pp[1];
          float pq[8] = {p0.x,p0.y,p0.z,p0.w,p1.x,p1.y,p1.z,p1.w};
          #pragma unroll
          for (int j = 0; j < 8; j++){
            // tanh(x) = 1 - 2/(exp(2x)+1); args pre-scaled by 2*log2(e) so exp2 works raw.
            float t = __builtin_amdgcn_exp2f(pq[j] + e[j]);
            acc[q] += vvv[j] * __builtin_amdgcn_rcpf(t + 1.0f);
          }
        }
      }
      #pragma unroll
      for (int q = 0; q < 8; q++){
        int qg = qt * 8 + q;
        int L = qg - 1; if (L < 1) L = 1;
        sc[q][k] = (k < L) ? (C - acc[q]) : -1e30f;
      }
    }
  }
  __syncthreads();
  // softmax: 32-lane group g handles query row g
  int g = tid >> 5, l = tid & 31;
  float m = -1e30f;
  for (int k = l; k < Lmax; k += 32) m = fmaxf(m, sc[g][k]);
  #pragma unroll
  for (int off = 16; off; off >>= 1) m = fmaxf(m, __shfl_xor(m, off, 32));
  const float LOG2E = 1.4426950408889634f;
  float ssum = 0.0f;
  for (int k = l; k < Lmax; k += 32){
    float e = __builtin_amdgcn_exp2f((sc[g][k] - m) * LOG2E);
    sc[g][k] = e; ssum += e;
  }
  #pragma unroll
  for (int off = 16; off; off >>= 1) ssum += __shfl_xor(ssum, off, 32);
  float rl = 1.0f / ssum;
  int qg = qt * 8 + g;
  // weights out: [q][k][b]; k >= Lmax stays zero from memset; k in [L, Lmax) writes exact 0.
  for (int k = l; k < Lmax; k += 32)
    wout[((long)qg * Sn + k) * Bn + b] = sc[g][k] * rl;
}

// ---------------- context[q][b][e] = sum_k w[q][k][b] * emb[k][b][e] ----------------
__global__ __launch_bounds__(256) void context_kernel(const float* __restrict__ w,
                                                      const float* __restrict__ emb,
                                                      float* __restrict__ ctx){
  __shared__ float xl[8][512];
  __shared__ float wl[8][8];
  int tid = threadIdx.x;
  int qt = gridDim.x - 1 - blockIdx.x;
  int b = blockIdx.y;
  int Lmax = qt * 8 + 6; if (Lmax < 1) Lmax = 1;
  int nch = (Lmax + 7) >> 3;
  float acc[8][2];
  #pragma unroll
  for (int q = 0; q < 8; q++){ acc[q][0] = 0.f; acc[q][1] = 0.f; }
  for (int ch = 0; ch < nch; ch++){
    int k0 = ch * 8;
    __syncthreads();
    if (tid < 64){
      int q = tid >> 3, kk = tid & 7;
      // zeros beyond L[q] guaranteed by memset + exact-0 softmax tail
      wl[q][kk] = w[((long)(qt * 8 + q) * Sn + k0 + kk) * Bn + b];
    }
    #pragma unroll
    for (int i = 0; i < 4; i++){
      int idx = i * 256 + tid;           // 0..1023 over 8 rows x 128 float4
      int kr = idx >> 7, col = (idx & 127) * 4;
      const float4* src = (const float4*)(emb + ((long)((k0 + kr) * Bn + b)) * En);
      *(float4*)&xl[kr][col] = src[idx & 127];
    }
    __syncthreads();
    #pragma unroll
    for (int kk = 0; kk < 8; kk++){
      float x0 = xl[kk][tid], x1 = xl[kk][tid + 256];
      #pragma unroll
      for (int q = 0; q < 8; q++){
        float wv = wl[q][kk];
        acc[q][0] += wv * x0;
        acc[q][1] += wv * x1;
      }
    }
  }
  #pragma unroll
  for (int q = 0; q < 8; q++){
    int qg = qt * 8 + q;
    float* dst = ctx + ((long)(qg * Bn + b)) * En;
    dst[tid]       = acc[q][0];
    dst[tid + 256] = acc[q][1];
  }
}

// ---------------- final: out[r][h] = outs[r][:].W_h2h[h][:] + b1[h] + ctx[r][:].W_e2h[h][:] + b2[h]
// NOTE: ctx aliases outp (same rows); each block stages its rows in LDS before writing.
__global__ __launch_bounds__(256) void final_kernel(const float* __restrict__ outsp,
                                                    const float* __restrict__ ctx,
                                                    const float* __restrict__ W1,
                                                    const float* __restrict__ b1,
                                                    const float* __restrict__ W2,
                                                    const float* __restrict__ b2,
                                                    float* __restrict__ outp){
  __shared__ float x1[8][512];
  __shared__ float x2[8][512];
  int tid = threadIdx.x;
  long r0 = (long)blockIdx.x * 8;
  const float4* s1 = (const float4*)(outsp + r0 * 512);
  const float4* s2 = (const float4*)(ctx + r0 * 512);
  #pragma unroll
  for (int i = 0; i < 4; i++){
    int idx = i * 256 + tid;
    int row = idx >> 7, col = (idx & 127) * 4;
    *(float4*)&x1[row][col] = s1[idx];
    *(float4*)&x2[row][col] = s2[idx];
  }
  __syncthreads();
  float acc[8][2];
  float bza = b1[tid] + b2[tid];
  float bzb = b1[tid + 256] + b2[tid + 256];
  #pragma unroll
  for (int r = 0; r < 8; r++){ acc[r][0] = bza; acc[r][1] = bzb; }
  const float4* w1a = (const float4*)(W1 + (long)tid * 512);
  const float4* w1b = (const float4*)(W1 + (long)(tid + 256) * 512);
  const float4* w2a = (const float4*)(W2 + (long)tid * 512);
  const float4* w2b = (const float4*)(W2 + (long)(tid + 256) * 512);
  for (int c = 0; c < 128; c++){
    float4 wa = w1a[c], wb = w1b[c], va = w2a[c], vb = w2b[c];
    int e0 = c * 4;
    #pragma unroll
    for (int r = 0; r < 8; r++){
      float4 x = *(const float4*)&x1[r][e0];
      float4 y = *(const float4*)&x2[r][e0];
      acc[r][0] += wa.x*x.x + wa.y*x.y + wa.z*x.z + wa.w*x.w
                 + va.x*y.x + va.y*y.y + va.z*y.z + va.w*y.w;
      acc[r][1] += wb.x*x.x + wb.y*x.y + wb.z*x.z + wb.w*x.w
                 + vb.x*y.x + vb.y*y.y + vb.z*y.z + vb.w*y.w;
    }
  }
  #pragma unroll
  for (int r = 0; r < 8; r++){
    long rr = r0 + r;
    outp[rr * 512 + tid]       = acc[r][0];
    outp[rr * 512 + tid + 256] = acc[r][1];
  }
}

extern "C" void kernel_launch(void* const* d_in, const int* in_sizes, int n_in,
                              void* d_out, int out_size, void* d_ws, size_t ws_size,
                              hipStream_t stream) {
  const float* outs  = (const float*)d_in[0];
  const float* emb   = (const float*)d_in[1];
  const float* W_enc = (const float*)d_in[2];
  const float* b_enc = (const float*)d_in[3];
  const float* W_dec = (const float*)d_in[4];
  const float* b_dec = (const float*)d_in[5];
  const float* v     = (const float*)d_in[6];
  const float* W_h2h = (const float*)d_in[7];
  const float* b_h2h = (const float*)d_in[8];
  const float* W_e2h = (const float*)d_in[9];
  const float* b_e2h = (const float*)d_in[10];

  float* out0 = (float*)d_out;                        // (S,B,H) = 16,777,216 f32
  float* outw = out0 + (size_t)Sn * Bn * Hn;          // (S,S,B) = 33,554,432 f32

  // NO d_ws usage. Scratch lives inside d_out's out0 region with phase aliasing:
  //   phase 1: eat [b][k][a] at out0[0..8388608), pat [b][s][a] at out0[8388608..16777216)
  //   phase 2 (after score): ctx [q*B+b][E] at out0[0..16777216)
  //   phase 3: final output overwrites out0 (block-local staged reads, no race)
  float* eat = out0;
  float* pat = out0 + (size_t)8388608;
  float* ctx = out0;

  hipMemsetAsync(outw, 0, (size_t)Sn * Sn * Bn * 4, stream);   // zero masked weights
  proj_kernel<<<2048, 256, 0, stream>>>(emb,  W_enc, b_enc, eat);
  proj_kernel<<<2048, 256, 0, stream>>>(outs, W_dec, b_dec, pat);
  score_kernel<<<dim3(128, 32), 256, 0, stream>>>(eat, pat, v, outw);
  context_kernel<<<dim3(128, 32), 256, 0, stream>>>(outw, emb, ctx);
  final_kernel<<<4096, 256, 0, stream>>>(outs, ctx, W_h2h, b_h2h, W_e2h, b_e2h, out0);
}